// Round 2
// baseline (11069.276 us; speedup 1.0000x reference)
//
#include <hip/hip_runtime.h>

// LSTM_HEAD: 167-step recurrence, BS=1024, HIDDEN=512, K=66+512=578.
// Round 1: same correctness-first fp32 VALU implementation (round 0 never ran
// — GPU acquisition timeout). K-loop unroll 2->4 for deeper load pipelining.
// Grid decomposition per step: 32 batch-groups x 16 unit-tiles = 512 WGs.
// One kernel launch per step (kernel boundary = grid sync for h / pred).

#define HIDDEN 512
#define SEQ    168
#define NSTEP  167   // seq_len - 1 predictions / steps
#define BS     1024
#define CTX    64
#define INPD   66    // 64 + y + hv
#define KDIM   578   // INPD + HIDDEN
#define PAD    34    // LDS row pitch (floats): even -> 8B-aligned float2 reads, 2-way-bank-free writes
#define BT     32    // batch tile per WG
#define UT     32    // hidden units per WG (x4 gates = 128 gate cols)

__device__ __forceinline__ float sigmoidf_(float x) {
    return 1.0f / (1.0f + __expf(-x));
}

// Init: h0 = 0, c0 = 0, out[:] = bo (atomicAdd partials accumulate on top).
__global__ void lstm_prep(float* __restrict__ h0, float* __restrict__ c_ws,
                          float* __restrict__ out, const float* __restrict__ bo_p) {
    const size_t i = (size_t)blockIdx.x * blockDim.x + threadIdx.x;
    const size_t stride = (size_t)gridDim.x * blockDim.x;
    const size_t nstate = (size_t)BS * HIDDEN;
    const float bo = *bo_p;
    for (size_t idx = i; idx < nstate; idx += stride) {
        h0[idx] = 0.0f;
        c_ws[idx] = 0.0f;
    }
    const size_t nout = (size_t)BS * NSTEP;
    for (size_t idx = i; idx < nout; idx += stride) {
        out[idx] = bo;
    }
}

__global__ __launch_bounds__(256, 2)
void lstm_step(const float* __restrict__ x_dyn, const float* __restrict__ y_flow,
               const float* __restrict__ W, const float* __restrict__ bias,
               const float* __restrict__ Wo, const int* __restrict__ twin_p,
               float* __restrict__ out, const float* __restrict__ h_read,
               float* __restrict__ h_write, float* __restrict__ c_ws, int t)
{
    extern __shared__ float smem[];  // inp_T: [KDIM][PAD], value at [k][b_local]
    const int tid = threadIdx.x;
    const int tx = tid & 31;   // unit within tile
    const int ty = tid >> 5;   // batch quad within tile (8 quads of 4)
    const int bid = blockIdx.x;
    const int gt = bid & 15;          // unit-tile index (16 tiles of 32 units)
    const int b0 = (bid >> 4) * BT;   // batch-group base (32 groups of 32)
    const int twin = *twin_p;

    // ---- stage x_t (transposed): smem[k][b] ----
    for (int idx = tid; idx < BT * CTX; idx += 256) {
        const int b = idx >> 6, k = idx & 63;
        smem[k * PAD + b] = x_dyn[((size_t)(b0 + b) * SEQ + t) * CTX + k];
    }
    // ---- stage y/last (col 64) and zeros/hv (col 65) ----
    if (tid < BT) {
        const int b = b0 + tid;
        float v64, v65;
        if (t < twin) {
            v64 = y_flow[(size_t)b * SEQ + t];
            v65 = 0.0f;
        } else {
            v64 = out[(size_t)b * NSTEP + (t - 1)];   // autoregressive feedback
            v65 = (float)(t - twin + 1) * (1.0f / 24.0f);
        }
        smem[64 * PAD + tid] = v64;
        smem[65 * PAD + tid] = v65;
    }
    // ---- stage h_prev (transposed): smem[66+u][b] ----
    for (int idx = tid; idx < BT * HIDDEN; idx += 256) {
        const int b = idx >> 9, u = idx & 511;
        smem[(INPD + u) * PAD + b] = h_read[(size_t)(b0 + b) * HIDDEN + u];
    }
    __syncthreads();

    // ---- gate GEMM: acc[j][g] for batch b0+ty*4+j, unit gt*32+tx, gate g ----
    float acc[4][4];
    #pragma unroll
    for (int j = 0; j < 4; ++j)
        #pragma unroll
        for (int g = 0; g < 4; ++g) acc[j][g] = 0.0f;

    const float* Wp = W + gt * UT + tx;   // + g*512 + k*2048
    const float* sp = smem + ty * 4;
    #pragma unroll 4
    for (int k = 0; k < KDIM; ++k) {
        const float w0 = Wp[(size_t)k * 2048];
        const float w1 = Wp[(size_t)k * 2048 + 512];
        const float w2 = Wp[(size_t)k * 2048 + 1024];
        const float w3 = Wp[(size_t)k * 2048 + 1536];
        const float2 pa = *(const float2*)(sp + k * PAD);
        const float2 pb = *(const float2*)(sp + k * PAD + 2);
        const float p0 = pa.x, p1 = pa.y, p2 = pb.x, p3 = pb.y;
        acc[0][0] = fmaf(p0, w0, acc[0][0]);
        acc[0][1] = fmaf(p0, w1, acc[0][1]);
        acc[0][2] = fmaf(p0, w2, acc[0][2]);
        acc[0][3] = fmaf(p0, w3, acc[0][3]);
        acc[1][0] = fmaf(p1, w0, acc[1][0]);
        acc[1][1] = fmaf(p1, w1, acc[1][1]);
        acc[1][2] = fmaf(p1, w2, acc[1][2]);
        acc[1][3] = fmaf(p1, w3, acc[1][3]);
        acc[2][0] = fmaf(p2, w0, acc[2][0]);
        acc[2][1] = fmaf(p2, w1, acc[2][1]);
        acc[2][2] = fmaf(p2, w2, acc[2][2]);
        acc[2][3] = fmaf(p2, w3, acc[2][3]);
        acc[3][0] = fmaf(p3, w0, acc[3][0]);
        acc[3][1] = fmaf(p3, w1, acc[3][1]);
        acc[3][2] = fmaf(p3, w2, acc[3][2]);
        acc[3][3] = fmaf(p3, w3, acc[3][3]);
    }

    // ---- pointwise LSTM cell + projection ----
    const int u = gt * UT + tx;
    const float bi = bias[u];
    const float bf = bias[512 + u];
    const float bg = bias[1024 + u];
    const float bo = bias[1536 + u];
    const float wo = Wo[u];
    #pragma unroll
    for (int j = 0; j < 4; ++j) {
        const int b = b0 + ty * 4 + j;
        const size_t cidx = (size_t)b * HIDDEN + u;
        const float i_ = sigmoidf_(acc[j][0] + bi);
        const float f_ = sigmoidf_(acc[j][1] + bf);
        const float g_ = tanhf(acc[j][2] + bg);
        const float o_ = sigmoidf_(acc[j][3] + bo);
        const float c = f_ * c_ws[cidx] + i_ * g_;
        c_ws[cidx] = c;
        const float h = o_ * tanhf(c);
        h_write[cidx] = h;
        // pred partial: reduce h*wo over the 32 units of this tile (lanes tx 0..31)
        float p = h * wo;
        #pragma unroll
        for (int m = 1; m < 32; m <<= 1) p += __shfl_xor(p, m);
        if (tx == 0) atomicAdd(&out[(size_t)b * NSTEP + t], p);
    }
}

extern "C" void kernel_launch(void* const* d_in, const int* in_sizes, int n_in,
                              void* d_out, int out_size, void* d_ws, size_t ws_size,
                              hipStream_t stream) {
    (void)in_sizes; (void)n_in; (void)out_size; (void)ws_size;
    const float* x_dyn  = (const float*)d_in[0];
    const float* y_flow = (const float*)d_in[1];
    const float* W      = (const float*)d_in[2];
    const float* bias   = (const float*)d_in[3];
    const float* Wo     = (const float*)d_in[4];
    const float* bo     = (const float*)d_in[5];
    const int*   twin   = (const int*)d_in[6];
    float* out = (float*)d_out;

    float* h0   = (float*)d_ws;                       // [BS*HIDDEN]
    float* h1   = h0 + (size_t)BS * HIDDEN;           // [BS*HIDDEN]
    float* c_ws = h1 + (size_t)BS * HIDDEN;           // [BS*HIDDEN]

    lstm_prep<<<dim3(512), dim3(256), 0, stream>>>(h0, c_ws, out, bo);

    const int lds_bytes = KDIM * PAD * (int)sizeof(float);   // 78,608 B
    for (int t = 0; t < NSTEP; ++t) {
        float* hr = (t & 1) ? h1 : h0;
        float* hw = (t & 1) ? h0 : h1;
        lstm_step<<<dim3(512), dim3(256), lds_bytes, stream>>>(
            x_dyn, y_flow, W, bias, Wo, twin, out, hr, hw, c_ws, t);
    }
}

// Round 7
// 5884.119 us; speedup vs baseline: 1.8812x; 1.8812x over previous
//
#include <hip/hip_runtime.h>

// LSTM_HEAD: MFMA hi/lo-split gate GEMM, 167-step recurrence.
// Round 6: NO cooperative launch (Round 4 proved it is rejected here ->
// untouched output). Per-step normal launches only — Round-2-proven
// mechanics: dynamic LDS <= 78.6KB, kernel boundary = grid sync.
// 512 WGs = 64 unit-tiles (8 units x 4 gates = 32 gate-cols) x 8 batch-tiles
// (128 batches). W tile staged to LDS as bf16 hi/lo each step (75.3KB).
// Gate GEMM: 3-pass hi/lo mfma_f32_16x16x32_bf16 (~fp32 accuracy), K=576.
// Scalar cols (y/last=64, hv=65) applied as fp32 rank-2 fixup.

#define HIDDEN 512
#define SEQ    168
#define NSTEP  167
#define BS     1024
#define CTX    64
#define KM     576       // MFMA K: x cols 0-63 | h cols 64-575 (W rows 66..577)
#define KP     584       // LDS k-pitch (ushorts): 1168B rows -> conflict-free b128
#define MTILE  128       // batches per WG
#define SGRID  512       // step grid: 64 unit-tiles x 8 batch-tiles
#define PGRID  256
#define NTHR   256

typedef __attribute__((ext_vector_type(8))) short s16x8;
typedef __attribute__((ext_vector_type(4))) float f32x4;

static __device__ __forceinline__ unsigned short bf16_rne(float f) {
    union { float f; unsigned int u; } v; v.f = f;
    unsigned int r = v.u + 0x7FFFu + ((v.u >> 16) & 1u);
    return (unsigned short)(r >> 16);
}
static __device__ __forceinline__ float bf16_to_f(unsigned short h) {
    union { float f; unsigned int u; } v; v.u = ((unsigned int)h) << 16;
    return v.f;
}
static __device__ __forceinline__ float sigmoid_(float x) {
    x = fminf(fmaxf(x, -80.f), 80.f);
    return 1.0f / (1.0f + __expf(-x));
}
static __device__ __forceinline__ float tanh_(float x) {
    float ax = fminf(fabsf(x), 40.f);
    float e = __expf(-2.0f * ax);
    float r = (1.0f - e) / (1.0f + e);
    return copysignf(r, x);
}

// ---- init: out = bo, c = 0, A[parity0] = {x_dyn[:,0] | h0=0} ----
__global__ void lstm_prep(const float* __restrict__ x_dyn, float* __restrict__ out,
                          const float* __restrict__ bo_p,
                          unsigned short* __restrict__ aHi, unsigned short* __restrict__ aLo,
                          float* __restrict__ cst)
{
    const int gthr = blockIdx.x * NTHR + threadIdx.x;
    const int gstr = PGRID * NTHR;
    const float bo = *bo_p;
    for (int i = gthr; i < BS * NSTEP; i += gstr) out[i] = bo;
    for (int i = gthr; i < BS * HIDDEN; i += gstr) cst[i] = 0.f;
    for (int i = gthr; i < BS * 256; i += gstr) {        // h-cols 64..575 (256 uints/row)
        const int b = i >> 8, j = i & 255;
        ((unsigned int*)aHi)[b * 288 + 32 + j] = 0u;
        ((unsigned int*)aLo)[b * 288 + 32 + j] = 0u;
    }
    for (int i = gthr; i < BS * CTX; i += gstr) {        // x-cols 0..63 at t=0
        const int b = i >> 6, col = i & 63;
        const float v = x_dyn[(size_t)b * SEQ * CTX + col];
        const unsigned short hi = bf16_rne(v);
        aHi[(size_t)b * KM + col] = hi;
        aLo[(size_t)b * KM + col] = bf16_rne(v - bf16_to_f(hi));
    }
}

__global__ __launch_bounds__(NTHR, 2)
void lstm_step(const float* __restrict__ x_dyn, const float* __restrict__ y_flow,
               const float* __restrict__ Wg, const float* __restrict__ bias,
               const float* __restrict__ Wo, const int* __restrict__ twin_p,
               float* __restrict__ out, unsigned short* __restrict__ aHi,
               unsigned short* __restrict__ aLo, float* __restrict__ cst, int t)
{
    extern __shared__ unsigned char smem_raw[];
    unsigned short* whi = (unsigned short*)smem_raw;     // [32][KP]
    unsigned short* wlo = whi + 32 * KP;                 // [32][KP]
    float* a64s = (float*)(wlo + 32 * KP);               // [128] y/last per local batch

    const int tid = threadIdx.x, bid = blockIdx.x;
    const int nt = bid >> 3;            // unit tile 0..63 (units nt*8..nt*8+7)
    const int m0 = (bid & 7) * MTILE;   // batch tile; bid%8 keeps tile on one XCD
    const int lane = tid & 63, wv = tid >> 6;
    const int ln15 = lane & 15, kg = lane >> 4;
    const int twin = *twin_p;

    const int par = t & 1, pn = par ^ 1;
    const unsigned short* aH = aHi + (size_t)par * BS * KM;
    const unsigned short* aL = aLo + (size_t)par * BS * KM;
    unsigned short* nH = aHi + (size_t)pn * BS * KM;
    unsigned short* nL = aLo + (size_t)pn * BS * KM;
    const float hv = (t < twin) ? 0.f : (float)(t - twin + 1) * (1.f / 24.f);

    // ---- stage this WG's W tile (32 gate-cols x K=576) to LDS as bf16 hi/lo ----
    // LDS row c (0..31): ns=c>>4, j=c&15 -> gate = 2*ns + (j>>3), unit = nt*8 + (j&7)
    for (int idx = tid; idx < 32 * KM; idx += NTHR) {
        const int k = idx >> 5, c = idx & 31;
        const int wrow = (k < 64) ? k : (k + 2);         // skip rows 64,65 (fixup)
        const int wcol = (2 * (c >> 4) + ((c >> 3) & 1)) * 512 + nt * 8 + (c & 7);
        const float v = Wg[(size_t)wrow * 2048 + wcol];
        const unsigned short hi = bf16_rne(v);
        whi[c * KP + k] = hi;
        wlo[c * KP + k] = bf16_rne(v - bf16_to_f(hi));
    }

    // ---- stage y/last column for this WG's 128 batches ----
    if (tid < MTILE) {
        const int b = m0 + tid;
        float v;
        if (t < twin) v = y_flow[(size_t)b * SEQ + t];
        else if (t > 0) v = out[(size_t)b * NSTEP + (t - 1)];  // finalized by prev kernel
        else v = 0.f;
        a64s[tid] = v;
    }
    __syncthreads();

    // ---- x-refresh for step t+1 into other parity (2 batches per nt-WG) ----
    if (tid < 128) {
        const int b = m0 + nt * 2 + (tid >> 6), col = tid & 63;
        const float v = x_dyn[((size_t)b * SEQ + (t + 1)) * CTX + col];
        const unsigned short hi = bf16_rne(v);
        nH[(size_t)b * KM + col] = hi;
        nL[(size_t)b * KM + col] = bf16_rne(v - bf16_to_f(hi));
    }

    // ---- per-lane constants: fixup rows 64/65, bias, Wo ----
    float w64c[2], basec[2];
    #pragma unroll
    for (int ns = 0; ns < 2; ++ns) {
        const int wcol = (2 * ns + (ln15 >> 3)) * 512 + nt * 8 + (ln15 & 7);
        w64c[ns]  = Wg[(size_t)64 * 2048 + wcol];
        basec[ns] = fmaf(hv, Wg[(size_t)65 * 2048 + wcol], bias[wcol]);
    }
    const int u = nt * 8 + (ln15 & 7);
    const float wo_u = Wo[u];
    const bool lo_half = (ln15 < 8);

    // ---- gate GEMM: 3-pass hi/lo bf16 MFMA over K=576 ----
    const size_t aoff0 = (size_t)(m0 + wv * 32 + ln15) * KM + kg * 8;
    const size_t aoff1 = aoff0 + (size_t)16 * KM;

    f32x4 acc[2][2];
    #pragma unroll
    for (int ms = 0; ms < 2; ++ms)
        #pragma unroll
        for (int ns = 0; ns < 2; ++ns) acc[ms][ns] = (f32x4){0.f, 0.f, 0.f, 0.f};

    s16x8 ah[2][2], al[2][2];
    ah[0][0] = *(const s16x8*)(aH + aoff0);
    ah[0][1] = *(const s16x8*)(aH + aoff1);
    al[0][0] = *(const s16x8*)(aL + aoff0);
    al[0][1] = *(const s16x8*)(aL + aoff1);

    #pragma unroll
    for (int kc = 0; kc < 18; ++kc) {
        const int cur = kc & 1, nxt = cur ^ 1;
        const int k0 = kc * 32;
        if (kc < 17) {   // prefetch next chunk's A-fragments
            ah[nxt][0] = *(const s16x8*)(aH + aoff0 + k0 + 32);
            ah[nxt][1] = *(const s16x8*)(aH + aoff1 + k0 + 32);
            al[nxt][0] = *(const s16x8*)(aL + aoff0 + k0 + 32);
            al[nxt][1] = *(const s16x8*)(aL + aoff1 + k0 + 32);
        }
        s16x8 bh[2], bl[2];
        #pragma unroll
        for (int ns = 0; ns < 2; ++ns) {
            const int boff = (ns * 16 + ln15) * KP + k0 + kg * 8;
            bh[ns] = *(const s16x8*)(whi + boff);
            bl[ns] = *(const s16x8*)(wlo + boff);
        }
        #pragma unroll
        for (int ns = 0; ns < 2; ++ns)
            #pragma unroll
            for (int ms = 0; ms < 2; ++ms) {
                acc[ms][ns] = __builtin_amdgcn_mfma_f32_16x16x32_bf16(ah[cur][ms], bh[ns], acc[ms][ns], 0, 0, 0);
                acc[ms][ns] = __builtin_amdgcn_mfma_f32_16x16x32_bf16(ah[cur][ms], bl[ns], acc[ms][ns], 0, 0, 0);
                acc[ms][ns] = __builtin_amdgcn_mfma_f32_16x16x32_bf16(al[cur][ms], bh[ns], acc[ms][ns], 0, 0, 0);
            }
    }

    // ---- fixup + gate-transpose (xor 8) + cell + h/pred ----
    // lane ln15: own ns=0 -> gate (ln15>>3), ns=1 -> gate 2+(ln15>>3); partner
    // (ln15^8) holds the other two gates of the same unit.
    #pragma unroll
    for (int ms = 0; ms < 2; ++ms) {
        #pragma unroll
        for (int r = 0; r < 4; ++r) {
            const int rl = wv * 32 + ms * 16 + kg * 4 + r;   // C/D: row=(lane>>4)*4+reg
            const int b = m0 + rl;
            const float a64v = a64s[rl];
            const float pre0 = acc[ms][0][r] + fmaf(a64v, w64c[0], basec[0]);
            const float pre1 = acc[ms][1][r] + fmaf(a64v, w64c[1], basec[1]);
            const float q0 = __shfl_xor(pre0, 8, 16);
            const float q1 = __shfl_xor(pre1, 8, 16);
            const float pi = lo_half ? pre0 : q0;
            const float pf = lo_half ? q0 : pre0;
            const float pg = lo_half ? pre1 : q1;
            const float po = lo_half ? q1 : pre1;
            const float i_ = sigmoid_(pi);
            const float f_ = sigmoid_(pf);
            const float g_ = tanh_(pg);
            const float o_ = sigmoid_(po);
            const size_t ci = (size_t)b * HIDDEN + u;
            const float c = f_ * cst[ci] + i_ * g_;
            const float h = o_ * tanh_(c);
            if (lo_half) {   // lanes l and l^8 computed identical (b,u) results
                cst[ci] = c;
                const unsigned short hh = bf16_rne(h);
                nH[(size_t)b * KM + 64 + u] = hh;
                nL[(size_t)b * KM + 64 + u] = bf16_rne(h - bf16_to_f(hh));
            }
            float p = lo_half ? h * wo_u : 0.f;
            p += __shfl_xor(p, 1, 16);
            p += __shfl_xor(p, 2, 16);
            p += __shfl_xor(p, 4, 16);
            p += __shfl_xor(p, 8, 16);
            if (ln15 == 0) atomicAdd(&out[(size_t)b * NSTEP + t], p);
        }
    }
}

extern "C" void kernel_launch(void* const* d_in, const int* in_sizes, int n_in,
                              void* d_out, int out_size, void* d_ws, size_t ws_size,
                              hipStream_t stream) {
    (void)in_sizes; (void)n_in; (void)out_size; (void)ws_size;
    const float* x_dyn  = (const float*)d_in[0];
    const float* y_flow = (const float*)d_in[1];
    const float* Wg     = (const float*)d_in[2];
    const float* bias   = (const float*)d_in[3];
    const float* Wo     = (const float*)d_in[4];
    const float* bo     = (const float*)d_in[5];
    const int*   twin   = (const int*)d_in[6];
    float* out = (float*)d_out;

    unsigned short* aHi = (unsigned short*)d_ws;                 // [2][BS][KM]
    unsigned short* aLo = aHi + (size_t)2 * BS * KM;             // [2][BS][KM]
    float* cst = (float*)(aLo + (size_t)2 * BS * KM);            // [BS][HIDDEN]

    const unsigned int smem = (2u * 32u * KP) * 2u + MTILE * 4u; // 75,264 B

    // Defensive (Round 2 showed >64KB dynamic LDS works even without this).
    (void)hipFuncSetAttribute((const void*)lstm_step,
                              hipFuncAttributeMaxDynamicSharedMemorySize, (int)smem);

    lstm_prep<<<dim3(PGRID), dim3(NTHR), 0, stream>>>(x_dyn, out, bo, aHi, aLo, cst);

    for (int t = 0; t < NSTEP; ++t) {
        lstm_step<<<dim3(SGRID), dim3(NTHR), smem, stream>>>(
            x_dyn, y_flow, Wg, bias, Wo, twin, out, aHi, aLo, cst, t);
    }
}

// Round 10
// 5098.895 us; speedup vs baseline: 2.1709x; 1.1540x over previous
//
#include <hip/hip_runtime.h>

// LSTM_HEAD: MFMA hi/lo-split gate GEMM, 167-step recurrence.
// Round 10 = Round 8/9 resubmission (infra failures, never ran).
//  - wprep: one-time W -> bf16 hi/lo planes in d_ws, in final LDS layout.
//  - lstm_step stages W via global_load_lds (width 16), no VALU, no ds_write.
//  - A-fragments: 2 half-K batches of 36 up-front register loads (static
//    indices) so HBM/L2 latency is pipelined (Round 7: VGPR=44 = no prefetch).
// Grid: 512 WGs = 64 unit-tiles (8 units x 4 gates = 32 gate-cols) x 8
// batch-tiles (128 batches). Per-step normal launches (proven mechanics).

#define HIDDEN 512
#define SEQ    168
#define NSTEP  167
#define BS     1024
#define CTX    64
#define KM     576       // MFMA K: x cols 0-63 | h cols 64-575 (W rows 66..577)
#define KP     584       // LDS k-pitch (ushorts): 1168B rows -> conflict-free b128
#define MTILE  128       // batches per WG
#define SGRID  512       // step grid: 64 unit-tiles x 8 batch-tiles
#define PGRID  256
#define NTHR   256
#define WTELEM (2 * 32 * KP)          // 37,376 ushorts per nt tile (74,752 B)

typedef __attribute__((ext_vector_type(8))) short s16x8;
typedef __attribute__((ext_vector_type(4))) float f32x4;

static __device__ __forceinline__ unsigned short bf16_rne(float f) {
    union { float f; unsigned int u; } v; v.f = f;
    unsigned int r = v.u + 0x7FFFu + ((v.u >> 16) & 1u);
    return (unsigned short)(r >> 16);
}
static __device__ __forceinline__ float bf16_to_f(unsigned short h) {
    union { float f; unsigned int u; } v; v.u = ((unsigned int)h) << 16;
    return v.f;
}
static __device__ __forceinline__ float sigmoid_(float x) {
    x = fminf(fmaxf(x, -80.f), 80.f);
    return 1.0f / (1.0f + __expf(-x));
}
static __device__ __forceinline__ float tanh_(float x) {
    float ax = fminf(fabsf(x), 40.f);
    float e = __expf(-2.0f * ax);
    float r = (1.0f - e) / (1.0f + e);
    return copysignf(r, x);
}

// ---- init: out = bo, c = 0, A[parity0] = {x_dyn[:,0] | h0=0} ----
__global__ void lstm_prep(const float* __restrict__ x_dyn, float* __restrict__ out,
                          const float* __restrict__ bo_p,
                          unsigned short* __restrict__ aHi, unsigned short* __restrict__ aLo,
                          float* __restrict__ cst)
{
    const int gthr = blockIdx.x * NTHR + threadIdx.x;
    const int gstr = PGRID * NTHR;
    const float bo = *bo_p;
    for (int i = gthr; i < BS * NSTEP; i += gstr) out[i] = bo;
    for (int i = gthr; i < BS * HIDDEN; i += gstr) cst[i] = 0.f;
    for (int i = gthr; i < BS * 256; i += gstr) {        // h-cols 64..575 (256 uints/row)
        const int b = i >> 8, j = i & 255;
        ((unsigned int*)aHi)[b * 288 + 32 + j] = 0u;
        ((unsigned int*)aLo)[b * 288 + 32 + j] = 0u;
    }
    for (int i = gthr; i < BS * CTX; i += gstr) {        // x-cols 0..63 at t=0
        const int b = i >> 6, col = i & 63;
        const float v = x_dyn[(size_t)b * SEQ * CTX + col];
        const unsigned short hi = bf16_rne(v);
        aHi[(size_t)b * KM + col] = hi;
        aLo[(size_t)b * KM + col] = bf16_rne(v - bf16_to_f(hi));
    }
}

// ---- one-time: W (fp32) -> per-nt-tile bf16 hi/lo planes, padded LDS layout ----
// wpl[nt][plane][c][kp]: plane 0 = hi, 1 = lo; c = ns*16 + j where
// gate = 2*ns + (j>>3), unit = nt*8 + (j&7); kp 0..575 = K, 576..583 pad.
__global__ void wprep(const float* __restrict__ Wg, unsigned short* __restrict__ wpl)
{
    const int gthr = blockIdx.x * NTHR + threadIdx.x;
    const int gstr = PGRID * NTHR;
    for (int i = gthr; i < 64 * 32 * KP; i += gstr) {
        const int kp = i % KP;
        const int c  = (i / KP) & 31;
        const int nt = i / (KP * 32);
        unsigned short hi = 0, lo = 0;
        if (kp < KM) {
            const int wrow = (kp < 64) ? kp : (kp + 2);  // skip rows 64,65 (fixup)
            const int wcol = (2 * (c >> 4) + ((c >> 3) & 1)) * 512 + nt * 8 + (c & 7);
            const float v = Wg[(size_t)wrow * 2048 + wcol];
            hi = bf16_rne(v);
            lo = bf16_rne(v - bf16_to_f(hi));
        }
        const size_t base = (size_t)nt * WTELEM + (size_t)c * KP + kp;
        wpl[base] = hi;                       // plane 0
        wpl[base + 32 * KP] = lo;             // plane 1
    }
}

__global__ __launch_bounds__(NTHR, 2)
void lstm_step(const float* __restrict__ x_dyn, const float* __restrict__ y_flow,
               const float* __restrict__ Wg, const float* __restrict__ bias,
               const float* __restrict__ Wo, const int* __restrict__ twin_p,
               float* __restrict__ out, unsigned short* __restrict__ aHi,
               unsigned short* __restrict__ aLo, float* __restrict__ cst,
               const unsigned short* __restrict__ wpl, int t)
{
    extern __shared__ unsigned char smem_raw[];
    unsigned short* whi = (unsigned short*)smem_raw;     // [32][KP]
    unsigned short* wlo = whi + 32 * KP;                 // [32][KP]
    float* a64s = (float*)(wlo + 32 * KP);               // [128] y/last per local batch

    const int tid = threadIdx.x, bid = blockIdx.x;
    const int nt = bid >> 3;            // unit tile 0..63 (units nt*8..nt*8+7)
    const int m0 = (bid & 7) * MTILE;   // batch tile; bid%8 keeps tile on one XCD
    const int lane = tid & 63, wv = tid >> 6;
    const int ln15 = lane & 15, kg = lane >> 4;
    const int twin = *twin_p;

    const int par = t & 1, pn = par ^ 1;
    const unsigned short* aH = aHi + (size_t)par * BS * KM;
    const unsigned short* aL = aLo + (size_t)par * BS * KM;
    unsigned short* nH = aHi + (size_t)pn * BS * KM;
    unsigned short* nL = aLo + (size_t)pn * BS * KM;
    const float hv = (t < twin) ? 0.f : (float)(t - twin + 1) * (1.f / 24.f);

    // ---- stage W tile (74,752 B) global -> LDS, no VGPR round-trip ----
    const unsigned short* wsrc = wpl + (size_t)nt * WTELEM;
#if __has_builtin(__builtin_amdgcn_global_load_lds)
    // 73 chunks of 1 KiB (64 lanes x 16 B); wave-uniform LDS base + lane*16.
    for (int c = wv; c < 73; c += 4) {
        __builtin_amdgcn_global_load_lds(
            (const __attribute__((address_space(1))) void*)(wsrc + c * 512 + lane * 8),
            (__attribute__((address_space(3))) void*)(smem_raw + c * 1024),
            16, 0, 0);
    }
#else
    for (int idx = tid; idx < WTELEM / 8; idx += NTHR) {
        *(s16x8*)((unsigned short*)smem_raw + idx * 8) = *(const s16x8*)(wsrc + idx * 8);
    }
#endif

    // ---- stage y/last column for this WG's 128 batches ----
    if (tid < MTILE) {
        const int b = m0 + tid;
        float v;
        if (t < twin) v = y_flow[(size_t)b * SEQ + t];
        else if (t > 0) v = out[(size_t)b * NSTEP + (t - 1)];  // finalized by prev kernel
        else v = 0.f;
        a64s[tid] = v;
    }
    __syncthreads();   // compiler emits s_waitcnt vmcnt(0) before s_barrier

    // ---- x-refresh for step t+1 into other parity (2 batches per nt-WG) ----
    if (tid < 128) {
        const int b = m0 + nt * 2 + (tid >> 6), col = tid & 63;
        const float v = x_dyn[((size_t)b * SEQ + (t + 1)) * CTX + col];
        const unsigned short hi = bf16_rne(v);
        nH[(size_t)b * KM + col] = hi;
        nL[(size_t)b * KM + col] = bf16_rne(v - bf16_to_f(hi));
    }

    // ---- per-lane constants: fixup rows 64/65, bias, Wo ----
    float w64c[2], basec[2];
    #pragma unroll
    for (int ns = 0; ns < 2; ++ns) {
        const int wcol = (2 * ns + (ln15 >> 3)) * 512 + nt * 8 + (ln15 & 7);
        w64c[ns]  = Wg[(size_t)64 * 2048 + wcol];
        basec[ns] = fmaf(hv, Wg[(size_t)65 * 2048 + wcol], bias[wcol]);
    }
    const int u = nt * 8 + (ln15 & 7);
    const float wo_u = Wo[u];
    const bool lo_half = (ln15 < 8);

    // ---- gate GEMM: 3-pass hi/lo bf16 MFMA over K=576 ----
    const size_t aoff0 = (size_t)(m0 + wv * 32 + ln15) * KM + kg * 8;
    const size_t aoff1 = aoff0 + (size_t)16 * KM;

    f32x4 acc[2][2];
    #pragma unroll
    for (int ms = 0; ms < 2; ++ms)
        #pragma unroll
        for (int ns = 0; ns < 2; ++ns) acc[ms][ns] = (f32x4){0.f, 0.f, 0.f, 0.f};

    // K split into 2 halves of 9 chunks; all 36 A-fragment loads of a half
    // are issued up-front (static indices -> registers, loads pipelined).
    #pragma unroll
    for (int half = 0; half < 2; ++half) {
        s16x8 Ah[9][2], Al[9][2];
        #pragma unroll
        for (int j = 0; j < 9; ++j) {
            const size_t k0 = (size_t)(half * 9 + j) * 32;
            Ah[j][0] = *(const s16x8*)(aH + aoff0 + k0);
            Ah[j][1] = *(const s16x8*)(aH + aoff1 + k0);
            Al[j][0] = *(const s16x8*)(aL + aoff0 + k0);
            Al[j][1] = *(const s16x8*)(aL + aoff1 + k0);
        }
        #pragma unroll
        for (int j = 0; j < 9; ++j) {
            const int k0 = (half * 9 + j) * 32;
            s16x8 bh[2], bl[2];
            #pragma unroll
            for (int ns = 0; ns < 2; ++ns) {
                const int boff = (ns * 16 + ln15) * KP + k0 + kg * 8;
                bh[ns] = *(const s16x8*)(whi + boff);
                bl[ns] = *(const s16x8*)(wlo + boff);
            }
            #pragma unroll
            for (int ns = 0; ns < 2; ++ns)
                #pragma unroll
                for (int ms = 0; ms < 2; ++ms) {
                    acc[ms][ns] = __builtin_amdgcn_mfma_f32_16x16x32_bf16(Ah[j][ms], bh[ns], acc[ms][ns], 0, 0, 0);
                    acc[ms][ns] = __builtin_amdgcn_mfma_f32_16x16x32_bf16(Ah[j][ms], bl[ns], acc[ms][ns], 0, 0, 0);
                    acc[ms][ns] = __builtin_amdgcn_mfma_f32_16x16x32_bf16(Al[j][ms], bh[ns], acc[ms][ns], 0, 0, 0);
                }
        }
    }

    // ---- fixup + gate-transpose (xor 8) + cell + h/pred ----
    #pragma unroll
    for (int ms = 0; ms < 2; ++ms) {
        #pragma unroll
        for (int r = 0; r < 4; ++r) {
            const int rl = wv * 32 + ms * 16 + kg * 4 + r;   // C/D: row=(lane>>4)*4+reg
            const int b = m0 + rl;
            const float a64v = a64s[rl];
            const float pre0 = acc[ms][0][r] + fmaf(a64v, w64c[0], basec[0]);
            const float pre1 = acc[ms][1][r] + fmaf(a64v, w64c[1], basec[1]);
            const float q0 = __shfl_xor(pre0, 8, 16);
            const float q1 = __shfl_xor(pre1, 8, 16);
            const float pi = lo_half ? pre0 : q0;
            const float pf = lo_half ? q0 : pre0;
            const float pg = lo_half ? pre1 : q1;
            const float po = lo_half ? q1 : pre1;
            const float i_ = sigmoid_(pi);
            const float f_ = sigmoid_(pf);
            const float g_ = tanh_(pg);
            const float o_ = sigmoid_(po);
            const size_t ci = (size_t)b * HIDDEN + u;
            const float c = f_ * cst[ci] + i_ * g_;
            const float h = o_ * tanh_(c);
            if (lo_half) {   // lanes l and l^8 computed identical (b,u) results
                cst[ci] = c;
                const unsigned short hh = bf16_rne(h);
                nH[(size_t)b * KM + 64 + u] = hh;
                nL[(size_t)b * KM + 64 + u] = bf16_rne(h - bf16_to_f(hh));
            }
            float p = lo_half ? h * wo_u : 0.f;
            p += __shfl_xor(p, 1, 16);
            p += __shfl_xor(p, 2, 16);
            p += __shfl_xor(p, 4, 16);
            p += __shfl_xor(p, 8, 16);
            if (ln15 == 0) atomicAdd(&out[(size_t)b * NSTEP + t], p);
        }
    }
}

extern "C" void kernel_launch(void* const* d_in, const int* in_sizes, int n_in,
                              void* d_out, int out_size, void* d_ws, size_t ws_size,
                              hipStream_t stream) {
    (void)in_sizes; (void)n_in; (void)out_size; (void)ws_size;
    const float* x_dyn  = (const float*)d_in[0];
    const float* y_flow = (const float*)d_in[1];
    const float* Wg     = (const float*)d_in[2];
    const float* bias   = (const float*)d_in[3];
    const float* Wo     = (const float*)d_in[4];
    const float* bo     = (const float*)d_in[5];
    const int*   twin   = (const int*)d_in[6];
    float* out = (float*)d_out;

    unsigned short* aHi = (unsigned short*)d_ws;                 // [2][BS][KM]
    unsigned short* aLo = aHi + (size_t)2 * BS * KM;             // [2][BS][KM]
    float* cst = (float*)(aLo + (size_t)2 * BS * KM);            // [BS][HIDDEN]
    unsigned short* wpl = (unsigned short*)(cst + (size_t)BS * HIDDEN);  // [64][2][32][KP]

    const unsigned int smem = (2u * 32u * KP) * 2u + MTILE * 4u; // 75,264 B

    (void)hipFuncSetAttribute((const void*)lstm_step,
                              hipFuncAttributeMaxDynamicSharedMemorySize, (int)smem);

    lstm_prep<<<dim3(PGRID), dim3(NTHR), 0, stream>>>(x_dyn, out, bo, aHi, aLo, cst);
    wprep<<<dim3(PGRID), dim3(NTHR), 0, stream>>>(Wg, wpl);

    for (int t = 0; t < NSTEP; ++t) {
        lstm_step<<<dim3(SGRID), dim3(NTHR), smem, stream>>>(
            x_dyn, y_flow, Wg, bias, Wo, twin, out, aHi, aLo, cst, wpl, t);
    }
}